// Round 9
// baseline (45.998 us; speedup 1.0000x reference)
//
#include <hip/hip_runtime.h>

#define M_DIM 32
#define K_DIM 4096
#define N_DIM 12288
#define SPLITK 8
#define KPER  (K_DIM / SPLITK)     // 512 k per block
#define NT    (KPER / 32)          // 16 k-tiles of 32
#define BLK   512                  // 8 waves
#define NPB   128                  // n per block (8 waves x 16)

using bf16x8 = __attribute__((ext_vector_type(8))) short;
using f32x4  = __attribute__((ext_vector_type(4))) float;

typedef __attribute__((address_space(1))) const void GASV;
typedef __attribute__((address_space(3))) void LASV;

__device__ __forceinline__ short to_bf16(float f) {
    unsigned u = __float_as_uint(f);
    u += 0x7FFFu + ((u >> 16) & 1u);               // RNE
    return (short)(u >> 16);
}

// ints in [0,256) are exact in bf16; f32 mantissa bits [15:0] are zero -> take high16.
__device__ __forceinline__ bf16x8 pack_b(const int (&wv)[8]) {
    union { unsigned u[4]; bf16x8 v; } r;
    #pragma unroll
    for (int p = 0; p < 4; ++p) {
        unsigned a = __float_as_uint((float)wv[2 * p]);
        unsigned b = __float_as_uint((float)wv[2 * p + 1]);
        r.u[p] = __builtin_amdgcn_perm(b, a, 0x07060302);  // [b.hi16 | a.hi16]
    }
    return r.v;
}

// ---------------------------------------------------------------------------
// Prep: build ALL A-fragments once (256 KB) + rowsum. Block b: rowsum[b] and
// k-tiles [4b,4b+4). Frag elem j holds k = kt*32 + 8g + (j ^ (g&1)) — the
// g-parity pair-swap matches main's bank-XOR B read order, so A,B use the
// same (lane,elem)->k map and the MFMA contraction is exact.
// ---------------------------------------------------------------------------
__global__ __launch_bounds__(256) void qmm_prep(const float* __restrict__ x,
                                                short* __restrict__ frag,
                                                float* __restrict__ rowsum) {
    const int b   = blockIdx.x;                    // 0..31
    const int tid = threadIdx.x;

    __shared__ float red[256];
    const float4* xr = (const float4*)(x + (size_t)b * K_DIM);
    float s = 0.f;
    #pragma unroll
    for (int i = 0; i < K_DIM / 4 / 256; ++i) {
        float4 v = xr[tid + 256 * i];
        s += v.x + v.y + v.z + v.w;
    }
    red[tid] = s;
    __syncthreads();
    #pragma unroll
    for (int off = 128; off > 0; off >>= 1) {
        if (tid < off) red[tid] += red[tid + off];
        __syncthreads();
    }
    if (tid == 0) rowsum[b] = red[0];

    #pragma unroll
    for (int i = 0; i < 2; ++i) {
        const int s2   = i * 256 + tid;            // 0..511
        const int kt   = 4 * b + (s2 >> 7);
        const int h    = (s2 >> 6) & 1;
        const int lane = s2 & 63;
        const int g    = lane >> 4;
        const int g0   = g & 1;
        const int m    = 16 * h + (lane & 15);
        const float* xp = x + (size_t)m * K_DIM + kt * 32 + 8 * g;
        float p0 = xp[0], p1 = xp[1], p2 = xp[2], p3 = xp[3];
        float p4 = xp[4], p5 = xp[5], p6 = xp[6], p7 = xp[7];
        bf16x8 v;
        v[0] = to_bf16(g0 ? p1 : p0);  v[1] = to_bf16(g0 ? p0 : p1);
        v[2] = to_bf16(g0 ? p3 : p2);  v[3] = to_bf16(g0 ? p2 : p3);
        v[4] = to_bf16(g0 ? p5 : p4);  v[5] = to_bf16(g0 ? p4 : p5);
        v[6] = to_bf16(g0 ? p7 : p6);  v[7] = to_bf16(g0 ? p6 : p7);
        *(bf16x8*)&frag[(size_t)((kt * 2 + h) * 64 + lane) * 8] = v;
    }
}

// ---------------------------------------------------------------------------
// Main: MFMA bf16 GEMM on raw u8 weights. ZERO barriers. Per wave: private
// 2-deep B ring in LDS (DMA'd via global_load_lds dwordx4), A-frags streamed
// to registers from ws (coalesced, L2-hot). Counted vmcnt only; 4 VMEM
// ops/tile (B,B,A,A). ds_read banking: linear DMA placement + XOR'd read
// bases (be/bo) -> each read 2 lanes/bank (free).
// ---------------------------------------------------------------------------
template <bool WS>
__global__ __launch_bounds__(BLK, 4) void qmm_main(const short* __restrict__ frag,
                                                   const int* __restrict__ w,
                                                   float* __restrict__ dst) {
    __shared__ int lds_b[8 * 2 * 512];             // 32 KB: 8 waves x ring2 x 2KB

    const int tid  = threadIdx.x;
    const int lane = tid & 63;
    const int g    = lane >> 4;
    const int g0   = g & 1;
    const int c    = lane & 15;
    const int wid  = tid >> 6;
    const int k0   = blockIdx.y * KPER;
    const int n0w  = blockIdx.x * NPB + wid * 16;

    // B DMA source: instr q, lane l -> row 16q + (l>>2), cols 4*(l&3)..+3
    const int* gsrc[2];
    #pragma unroll
    for (int q = 0; q < 2; ++q)
        gsrc[q] = w + (size_t)(k0 + 16 * q + (lane >> 2)) * N_DIM + n0w + 4 * (lane & 3);

    int* const wbase = &lds_b[wid * 1024];         // ring2 x 512 dwords

    // read bases (bytes): vb = 4*(128g + 4*(c>>2) + (c&3)); even j: be+64j, odd j: bo+64*(j-1)
    const int vb = 4 * (128 * g + 4 * (c >> 2) + (c & 3));
    const int be = vb + 64 * g0;
    const int bo = vb + 64 * (1 - g0);

    const short* asrc = frag + ((size_t)(blockIdx.y * NT) * 1024 + lane * 8);

    f32x4 acc0 = {0.f, 0.f, 0.f, 0.f};            // m in [0,16)
    f32x4 acc1 = {0.f, 0.f, 0.f, 0.f};            // m in [16,32)
    bf16x8 aA0, aA1, aB0, aB1;                     // A ring (t parity)

#define ISSUE(T) do {                                                            \
    __builtin_amdgcn_sched_barrier(0);                                           \
    __builtin_amdgcn_global_load_lds((GASV*)(gsrc[0] + (size_t)(32 * (T)) * N_DIM), \
        (LASV*)(wbase + ((T) & 1) * 512),       16, 0, 0);                       \
    __builtin_amdgcn_global_load_lds((GASV*)(gsrc[1] + (size_t)(32 * (T)) * N_DIM), \
        (LASV*)(wbase + ((T) & 1) * 512 + 256), 16, 0, 0);                       \
    if ((T) & 1) { aB0 = *(const bf16x8*)(asrc + (T) * 1024);                    \
                   aB1 = *(const bf16x8*)(asrc + (T) * 1024 + 512); }            \
    else         { aA0 = *(const bf16x8*)(asrc + (T) * 1024);                    \
                   aA1 = *(const bf16x8*)(asrc + (T) * 1024 + 512); }            \
    __builtin_amdgcn_sched_barrier(0);                                           \
} while (0)

#define WAITV(N) do { asm volatile("s_waitcnt vmcnt(" #N ")" ::: "memory");      \
    __builtin_amdgcn_sched_barrier(0); } while (0)

#define COMP(T) do {                                                             \
    char* pb = (char*)wbase + ((T) & 1) * 2048;                                  \
    int wv[8];                                                                   \
    wv[0] = *(int*)(pb + be);        wv[1] = *(int*)(pb + bo);                   \
    wv[2] = *(int*)(pb + be + 128);  wv[3] = *(int*)(pb + bo + 128);             \
    wv[4] = *(int*)(pb + be + 256);  wv[5] = *(int*)(pb + bo + 256);             \
    wv[6] = *(int*)(pb + be + 384);  wv[7] = *(int*)(pb + bo + 384);             \
    bf16x8 bfv = pack_b(wv);                                                     \
    acc0 = __builtin_amdgcn_mfma_f32_16x16x32_bf16(((T) & 1) ? aB0 : aA0, bfv, acc0, 0, 0, 0); \
    acc1 = __builtin_amdgcn_mfma_f32_16x16x32_bf16(((T) & 1) ? aB1 : aA1, bfv, acc1, 0, 0, 0); \
} while (0)

    ISSUE(0); ISSUE(1);
    WAITV(4); COMP(0);  ISSUE(2);
    WAITV(4); COMP(1);  ISSUE(3);
    WAITV(4); COMP(2);  ISSUE(4);
    WAITV(4); COMP(3);  ISSUE(5);
    WAITV(4); COMP(4);  ISSUE(6);
    WAITV(4); COMP(5);  ISSUE(7);
    WAITV(4); COMP(6);  ISSUE(8);
    WAITV(4); COMP(7);  ISSUE(9);
    WAITV(4); COMP(8);  ISSUE(10);
    WAITV(4); COMP(9);  ISSUE(11);
    WAITV(4); COMP(10); ISSUE(12);
    WAITV(4); COMP(11); ISSUE(13);
    WAITV(4); COMP(12); ISSUE(14);
    WAITV(4); COMP(13); ISSUE(15);
    WAITV(4); COMP(14);
    WAITV(0); COMP(15);

#undef ISSUE
#undef WAITV
#undef COMP

    // epilogue: C/D layout (HW-verified): row = 4*(lane>>4)+i, col = lane&15
    if (WS) {
        float* pp = dst + ((size_t)blockIdx.y * M_DIM) * N_DIM + n0w + c;
        #pragma unroll
        for (int i = 0; i < 4; ++i) {
            const int r = 4 * (lane >> 4) + i;
            pp[(size_t)r * N_DIM]        = acc0[i];
            pp[(size_t)(16 + r) * N_DIM] = acc1[i];
        }
    } else {
        #pragma unroll
        for (int i = 0; i < 4; ++i) {
            const int r = 4 * (lane >> 4) + i;
            atomicAdd(&dst[(size_t)r * N_DIM + n0w + c], acc0[i]);
            atomicAdd(&dst[(size_t)(16 + r) * N_DIM + n0w + c], acc1[i]);
        }
    }
}

// out[m,n] = scale[n] * (sum_s part[s][m][n] - zero[n] * rowsum[m]), float4-wide
__global__ __launch_bounds__(256) void qmm_finalize(const float* __restrict__ part,
                                                    const float* __restrict__ rowsum,
                                                    const float* __restrict__ scale,
                                                    const float* __restrict__ zero,
                                                    float* __restrict__ out) {
    const int m  = blockIdx.y;
    const int n4 = blockIdx.x * 256 + threadIdx.x;
    const float rs = rowsum[m];
    float4 acc = make_float4(0.f, 0.f, 0.f, 0.f);
    #pragma unroll
    for (int sp = 0; sp < SPLITK; ++sp) {
        float4 p = ((const float4*)(part + ((size_t)sp * M_DIM + m) * N_DIM))[n4];
        acc.x += p.x; acc.y += p.y; acc.z += p.z; acc.w += p.w;
    }
    const float4 sc = ((const float4*)scale)[n4];
    const float4 zp = ((const float4*)zero)[n4];
    float4 o;
    o.x = sc.x * (acc.x - zp.x * rs);
    o.y = sc.y * (acc.y - zp.y * rs);
    o.z = sc.z * (acc.z - zp.z * rs);
    o.w = sc.w * (acc.w - zp.w * rs);
    ((float4*)(out + (size_t)m * N_DIM))[n4] = o;
}

// Fallback path (ws too small for partials): atomic accumulate + self-contained scale
__global__ __launch_bounds__(256) void qmm_zero(float* __restrict__ out) {
    int i = blockIdx.x * 256 + threadIdx.x;
    ((float4*)out)[i] = make_float4(0.f, 0.f, 0.f, 0.f);
}
__global__ __launch_bounds__(256) void qmm_scale(const float* __restrict__ x,
                                                 const float* __restrict__ scale,
                                                 const float* __restrict__ zero,
                                                 float* __restrict__ out) {
    const int m = blockIdx.y;
    __shared__ float red[256];
    float s = 0.f;
    for (int k = threadIdx.x; k < K_DIM; k += 256)
        s += x[(size_t)m * K_DIM + k];
    red[threadIdx.x] = s;
    __syncthreads();
    #pragma unroll
    for (int off = 128; off > 0; off >>= 1) {
        if (threadIdx.x < off) red[threadIdx.x] += red[threadIdx.x + off];
        __syncthreads();
    }
    const float rowsum = red[0];
    const int n = blockIdx.x * 256 + threadIdx.x;
    const float v = out[(size_t)m * N_DIM + n];
    out[(size_t)m * N_DIM + n] = scale[n] * (v - zero[n] * rowsum);
}

extern "C" void kernel_launch(void* const* d_in, const int* in_sizes, int n_in,
                              void* d_out, int out_size, void* d_ws, size_t ws_size,
                              hipStream_t stream) {
    const float* x     = (const float*)d_in[0];
    const int*   w     = (const int*)d_in[1];
    const float* scale = (const float*)d_in[2];   // fp16 in reference; harness delivers fp32
    const float* zero  = (const float*)d_in[3];
    float* out = (float*)d_out;

    const size_t frag_sz = (size_t)128 * 2 * 64 * 8 * sizeof(short);            // 256 KB
    const size_t part_sz = (size_t)SPLITK * M_DIM * N_DIM * sizeof(float);      // 12.6 MB
    short* fragp  = (short*)d_ws;
    float* rowsum = (float*)((char*)d_ws + frag_sz);
    float* part   = (float*)((char*)d_ws + frag_sz + 256);

    if (ws_size >= frag_sz + 256 + part_sz) {
        qmm_prep    <<<dim3(32),                 dim3(256), 0, stream>>>(x, fragp, rowsum);
        qmm_main<true><<<dim3(N_DIM / NPB, SPLITK), dim3(BLK), 0, stream>>>(fragp, w, part);
        qmm_finalize<<<dim3(N_DIM / 4 / 256, M_DIM), dim3(256), 0, stream>>>(part, rowsum, scale, zero, out);
    } else {
        qmm_prep    <<<dim3(32),                 dim3(256), 0, stream>>>(x, fragp, rowsum);
        qmm_zero    <<<dim3((M_DIM * N_DIM / 4) / 256), dim3(256), 0, stream>>>(out);
        qmm_main<false><<<dim3(N_DIM / NPB, SPLITK), dim3(BLK), 0, stream>>>(fragp, w, out);
        qmm_scale   <<<dim3(N_DIM / 256, M_DIM), dim3(256), 0, stream>>>(x, scale, zero, out);
    }
}